// Round 8
// baseline (57.846 us; speedup 1.0000x reference)
//
#include <hip/hip_runtime.h>
#include <math.h>

// SeesawLoss forward: B=8192 rows, C=4096 classes, P=0.8, Q=2.0, EPS=0.01
// nll_b = M2' + log(sum_j exp(logit_bj - M2')) - o_{b,t}
// logit_bj = o_bj + P*(la_j - la_t)[la_j < la_t] + Q*(o_j - Koff)[> 0]
// Koff = M + lse1 + logclip;  logclip = max(o_t - M - lse1, log(EPS)).
// M2' = M + max(0, Q*(M-Koff)): analytic upper bound on all logits
// (mitigation <= 0, compensation <= Q*max(0,M-Koff)); slack <= ~12 ->
// exp(-12) relative error, far under threshold. Saves the 3rd pass.
//
// This round: ONE WAVE PER ROW. 64 floats/lane as 16 *named* float4s
// (macro-generated — no addressable array, rule #20). Zero LDS, zero
// __syncthreads in k_row; reductions are 6-step __shfl_xor only. 4 rows
// per 256-thread block. NO grid-wide atomics (R4/R5: same-address device
// atomics + fence from 8192 blocks serialize ~670us across 8 XCDs).

#define CC 4096

__device__ __forceinline__ float wave_max(float v) {
    #pragma unroll
    for (int o = 32; o > 0; o >>= 1) v = fmaxf(v, __shfl_xor(v, o, 64));
    return v;
}
__device__ __forceinline__ float wave_sum(float v) {
    #pragma unroll
    for (int o = 32; o > 0; o >>= 1) v += __shfl_xor(v, o, 64);
    return v;
}

__device__ __forceinline__ float esum4(float4 v, float M) {
    return (__expf(v.x - M) + __expf(v.y - M)) +
           (__expf(v.z - M) + __expf(v.w - M));
}

__device__ __forceinline__ float seesaw1(float o, float la, float la_t,
                                         float Koff) {
    float mit = (la < la_t) ? 0.8f * (la - la_t) : 0.f;   // mitigation  (<= 0)
    float d   = o - Koff;
    float cmp = (d > 0.f) ? 2.0f * d : 0.f;               // compensation (>= 0)
    return o + mit + cmp;                                 // == o at j==t
}

__device__ __forceinline__ float lsum4(float4 v, float4 la, float la_t,
                                       float Koff, float M2) {
    float a = __expf(seesaw1(v.x, la.x, la_t, Koff) - M2);
    float b = __expf(seesaw1(v.y, la.y, la_t, Koff) - M2);
    float c = __expf(seesaw1(v.z, la.z, la_t, Koff) - M2);
    float d = __expf(seesaw1(v.w, la.w, la_t, Koff) - M2);
    return (a + b) + (c + d);
}

// One block: bincount via LDS atomics -> clamp -> log table.
__global__ __launch_bounds__(1024) void k_hist(const int* __restrict__ tg, int B,
                                               float* __restrict__ logacc) {
    __shared__ int hacc[CC];
    const int tid = threadIdx.x;
    #pragma unroll
    for (int k = 0; k < CC / 1024; ++k) hacc[tid + k * 1024] = 0;
    __syncthreads();
    const int4* __restrict__ tg4 = (const int4*)tg;
    for (int i = tid; i < B / 4; i += 1024) {
        int4 tv = tg4[i];
        atomicAdd(&hacc[tv.x], 1); atomicAdd(&hacc[tv.y], 1);
        atomicAdd(&hacc[tv.z], 1); atomicAdd(&hacc[tv.w], 1);
    }
    __syncthreads();
    #pragma unroll
    for (int k = 0; k < CC / 1024; ++k) {
        int i = tid + k * 1024;
        int a = hacc[i];
        if (a < 1) a = 1;                 // clamp(min=1)
        logacc[i] = __logf((float)a);
    }
}

#define ROW_EACH(OP) OP(0) OP(1) OP(2) OP(3) OP(4) OP(5) OP(6) OP(7) \
                     OP(8) OP(9) OP(10) OP(11) OP(12) OP(13) OP(14) OP(15)

__global__ __launch_bounds__(256, 4) void k_row(const float* __restrict__ outp,
                                                const int* __restrict__ tg,
                                                const float* __restrict__ logacc,
                                                float* __restrict__ nll) {
    const int lane = threadIdx.x & 63;
    const int b    = (blockIdx.x << 2) + (threadIdx.x >> 6);  // 1 wave = 1 row

    const float LOG_EPS = -4.605170185988091f;   // log(0.01)

    const float4* __restrict__ src = (const float4*)(outp + (size_t)b * CC);
    const float4* __restrict__ lac = (const float4*)logacc;

    // ---- whole row into registers: 16 named float4s (64 floats/lane) ----
#define DECL_V(i) float4 v##i = src[lane + (i << 6)];
    ROW_EACH(DECL_V)
#undef DECL_V

    // row scalars (uniform per wave; issue early to overlap)
    const int   t    = tg[b];
    const float o_t  = outp[(size_t)b * CC + t];
    const float la_t = logacc[t];

    // ---- lane-local max, then wave max (no LDS) ----
    float m = -3.4e38f;
#define VMX(i) m = fmaxf(m, fmaxf(fmaxf(v##i.x, v##i.y), fmaxf(v##i.z, v##i.w)));
    ROW_EACH(VMX)
#undef VMX
    const float M = wave_max(m);

    // ---- sum exp(o - M): 4 independent accumulators (ILP) ----
    float s0 = esum4(v0,  M) + esum4(v4,  M) + esum4(v8,  M) + esum4(v12, M);
    float s1 = esum4(v1,  M) + esum4(v5,  M) + esum4(v9,  M) + esum4(v13, M);
    float s2 = esum4(v2,  M) + esum4(v6,  M) + esum4(v10, M) + esum4(v14, M);
    float s3 = esum4(v3,  M) + esum4(v7,  M) + esum4(v11, M) + esum4(v15, M);
    const float S    = wave_sum((s0 + s1) + (s2 + s3));
    const float lse1 = __logf(S);

    const float ls_t    = o_t - M - lse1;
    const float logclip = fmaxf(ls_t, LOG_EPS);
    const float Koff    = M + lse1 + logclip;                // d_j = o_j - Koff
    const float M2      = M + fmaxf(0.f, 2.0f * (M - Koff)); // analytic bound

    // ---- fused logit + sum exp(logit - M2): 4 accumulators ----
    float z0 = lsum4(v0,  lac[lane          ], la_t, Koff, M2)
             + lsum4(v4,  lac[lane + (4<<6) ], la_t, Koff, M2)
             + lsum4(v8,  lac[lane + (8<<6) ], la_t, Koff, M2)
             + lsum4(v12, lac[lane + (12<<6)], la_t, Koff, M2);
    float z1 = lsum4(v1,  lac[lane + (1<<6) ], la_t, Koff, M2)
             + lsum4(v5,  lac[lane + (5<<6) ], la_t, Koff, M2)
             + lsum4(v9,  lac[lane + (9<<6) ], la_t, Koff, M2)
             + lsum4(v13, lac[lane + (13<<6)], la_t, Koff, M2);
    float z2 = lsum4(v2,  lac[lane + (2<<6) ], la_t, Koff, M2)
             + lsum4(v6,  lac[lane + (6<<6) ], la_t, Koff, M2)
             + lsum4(v10, lac[lane + (10<<6)], la_t, Koff, M2)
             + lsum4(v14, lac[lane + (14<<6)], la_t, Koff, M2);
    float z3 = lsum4(v3,  lac[lane + (3<<6) ], la_t, Koff, M2)
             + lsum4(v7,  lac[lane + (7<<6) ], la_t, Koff, M2)
             + lsum4(v11, lac[lane + (11<<6)], la_t, Koff, M2)
             + lsum4(v15, lac[lane + (15<<6)], la_t, Koff, M2);
    const float S2 = wave_sum((z0 + z1) + (z2 + z3));

    if (lane == 0) nll[b] = M2 + __logf(S2) - o_t;   // plain store, no atomics
}

// deterministic final mean: fixed strided partials + fixed tree
__global__ __launch_bounds__(1024) void k_reduce(const float* __restrict__ nll,
                                                 float* __restrict__ out, int B) {
    __shared__ float red[16];
    const int tid = threadIdx.x;
    const float4* __restrict__ n4 = (const float4*)nll;
    float s = 0.f;
    for (int i = tid; i < B / 4; i += 1024) {
        float4 v = n4[i];
        s += (v.x + v.y) + (v.z + v.w);
    }
    s = wave_sum(s);
    if ((tid & 63) == 0) red[tid >> 6] = s;
    __syncthreads();
    if (tid == 0) {
        float tsum = 0.f;
        #pragma unroll
        for (int k = 0; k < 16; ++k) tsum += red[k];
        out[0] = tsum / (float)B;
    }
}

extern "C" void kernel_launch(void* const* d_in, const int* in_sizes, int n_in,
                              void* d_out, int out_size, void* d_ws, size_t ws_size,
                              hipStream_t stream) {
    const float* outp = (const float*)d_in[0];   // [B, C] f32
    const int*   tg   = (const int*)d_in[1];     // [B] i32
    float*       out  = (float*)d_out;           // scalar f32

    const int B = in_sizes[1];                   // 8192 (C fixed at 4096)

    char*  ws     = (char*)d_ws;
    float* logacc = (float*)ws;                  // 16 KB
    float* nll    = (float*)(ws + 16384);        // B*4 = 32 KB

    k_hist  <<<1, 1024, 0, stream>>>(tg, B, logacc);
    k_row   <<<B / 4, 256, 0, stream>>>(outp, tg, logacc, nll);
    k_reduce<<<1, 1024, 0, stream>>>(nll, out, B);
}

// Round 9
// 38.774 us; speedup vs baseline: 1.4919x; 1.4919x over previous
//
#include <hip/hip_runtime.h>
#include <math.h>

// SeesawLoss forward: B=8192 rows, C=4096 classes, P=0.8, Q=2.0, EPS=0.01
// nll_b = M2' + log(sum_j exp(logit_bj - M2')) - o_{b,t}
// logit_bj = o_bj + P*(la_j - la_t)[la_j < la_t] + Q*(o_j - Koff)[> 0]
// Koff = M + lse1 + logclip;  logclip = max(o_t - M - lse1, log(EPS)).
// M2' = M + max(0, Q*(M-Koff)): analytic upper bound on all logits.
//
// Structure (best = R7, 37.4us): block-per-row, 16 floats/thread in 4 named
// float4s (24 VGPR — R8 showed 64 floats/lane spills: VGPR=64, 62MB scratch).
// This round: online-softmax joint (m,s) reduction fuses the max and sum
// barriers (3 -> 2), exp starts on lane-local max immediately; o_t/la_t
// scalar chain hoisted ahead of row loads. NO grid-wide atomics (R4/R5:
// same-address atomics + fence from 8192 blocks serialize ~670us).

#define CC 4096

__device__ __forceinline__ float wave_sum(float v) {
    #pragma unroll
    for (int o = 32; o > 0; o >>= 1) v += __shfl_xor(v, o, 64);
    return v;
}

__device__ __forceinline__ float esum4(float4 v, float M) {
    return (__expf(v.x - M) + __expf(v.y - M)) +
           (__expf(v.z - M) + __expf(v.w - M));
}

__device__ __forceinline__ float seesaw1(float o, float la, float la_t,
                                         float Koff) {
    float mit = (la < la_t) ? 0.8f * (la - la_t) : 0.f;   // mitigation  (<= 0)
    float d   = o - Koff;
    float cmp = (d > 0.f) ? 2.0f * d : 0.f;               // compensation (>= 0)
    return o + mit + cmp;                                 // == o at j==t
}

__device__ __forceinline__ float lsum4(float4 v, float4 la, float la_t,
                                       float Koff, float M2) {
    float a = __expf(seesaw1(v.x, la.x, la_t, Koff) - M2);
    float b = __expf(seesaw1(v.y, la.y, la_t, Koff) - M2);
    float c = __expf(seesaw1(v.z, la.z, la_t, Koff) - M2);
    float d = __expf(seesaw1(v.w, la.w, la_t, Koff) - M2);
    return (a + b) + (c + d);
}

// online-softmax merge: (m,s) <- merge((m,s),(m2,s2))
__device__ __forceinline__ void ms_merge(float& m, float& s, float m2, float s2) {
    float Mn = fmaxf(m, m2);
    s = s * __expf(m - Mn) + s2 * __expf(m2 - Mn);
    m = Mn;
}

// One block: bincount via LDS atomics -> clamp -> log table.
__global__ __launch_bounds__(1024) void k_hist(const int* __restrict__ tg, int B,
                                               float* __restrict__ logacc) {
    __shared__ int hacc[CC];
    const int tid = threadIdx.x;
    #pragma unroll
    for (int k = 0; k < CC / 1024; ++k) hacc[tid + k * 1024] = 0;
    __syncthreads();
    const int4* __restrict__ tg4 = (const int4*)tg;
    for (int i = tid; i < B / 4; i += 1024) {
        int4 tv = tg4[i];
        atomicAdd(&hacc[tv.x], 1); atomicAdd(&hacc[tv.y], 1);
        atomicAdd(&hacc[tv.z], 1); atomicAdd(&hacc[tv.w], 1);
    }
    __syncthreads();
    #pragma unroll
    for (int k = 0; k < CC / 1024; ++k) {
        int i = tid + k * 1024;
        int a = hacc[i];
        if (a < 1) a = 1;                 // clamp(min=1)
        logacc[i] = __logf((float)a);
    }
}

__global__ __launch_bounds__(256, 8) void k_row(const float* __restrict__ outp,
                                                const int* __restrict__ tg,
                                                const float* __restrict__ logacc,
                                                float* __restrict__ nll) {
    __shared__ float2 red_ms[4];
    __shared__ float  red_s2[4];

    const int b   = blockIdx.x;
    const int tid = threadIdx.x;
    const int w   = tid >> 6;
    const bool lane0 = (tid & 63) == 0;

    const float LOG_EPS = -4.605170185988091f;   // log(0.01)

    // ---- scalar chain first: t -> o_t, la_t (critical path to Koff) ----
    const int   t    = tg[b];
    const float o_t  = outp[(size_t)b * CC + t];
    const float la_t = logacc[t];

    const float4* __restrict__ src = (const float4*)(outp + (size_t)b * CC);
    const float4* __restrict__ lac = (const float4*)logacc;

    // ---- row into registers (16 floats/thread, named — rule #20) ----
    float4 v0 = src[tid];
    float4 v1 = src[tid + 256];
    float4 v2 = src[tid + 512];
    float4 v3 = src[tid + 768];

    // ---- lane-local max, exp-sum vs LOCAL max (no wait on block max) ----
    float m0 = fmaxf(fmaxf(v0.x, v0.y), fmaxf(v0.z, v0.w));
    float m1 = fmaxf(fmaxf(v1.x, v1.y), fmaxf(v1.z, v1.w));
    float m2 = fmaxf(fmaxf(v2.x, v2.y), fmaxf(v2.z, v2.w));
    float m3 = fmaxf(fmaxf(v3.x, v3.y), fmaxf(v3.z, v3.w));
    float m  = fmaxf(fmaxf(m0, m1), fmaxf(m2, m3));
    float s  = (esum4(v0, m) + esum4(v1, m)) + (esum4(v2, m) + esum4(v3, m));

    // ---- joint (m,s) wave reduction (6 shfl steps) ----
    #pragma unroll
    for (int o = 32; o > 0; o >>= 1) {
        float mo = __shfl_xor(m, o, 64);
        float so = __shfl_xor(s, o, 64);
        ms_merge(m, s, mo, so);
    }
    if (lane0) red_ms[w] = make_float2(m, s);
    __syncthreads();

    // cross-wave merge (uniform, all threads redundantly)
    float M = red_ms[0].x, S = red_ms[0].y;
    ms_merge(M, S, red_ms[1].x, red_ms[1].y);
    ms_merge(M, S, red_ms[2].x, red_ms[2].y);
    ms_merge(M, S, red_ms[3].x, red_ms[3].y);
    const float lse1 = __logf(S);

    const float ls_t    = o_t - M - lse1;
    const float logclip = fmaxf(ls_t, LOG_EPS);
    const float Koff    = M + lse1 + logclip;                // d_j = o_j - Koff
    const float M2      = M + fmaxf(0.f, 2.0f * (M - Koff)); // analytic bound

    // ---- fused logit + sum exp(logit - M2): 4 independent accumulators ----
    float z0 = lsum4(v0, lac[tid      ], la_t, Koff, M2);
    float z1 = lsum4(v1, lac[tid + 256], la_t, Koff, M2);
    float z2 = lsum4(v2, lac[tid + 512], la_t, Koff, M2);
    float z3 = lsum4(v3, lac[tid + 768], la_t, Koff, M2);
    float z  = wave_sum((z0 + z1) + (z2 + z3));
    if (lane0) red_s2[w] = z;
    __syncthreads();

    if (tid == 0) {
        float S2 = (red_s2[0] + red_s2[1]) + (red_s2[2] + red_s2[3]);
        nll[b] = M2 + __logf(S2) - o_t;            // plain store, no atomics
    }
}

// deterministic final mean: fixed strided partials + fixed tree
__global__ __launch_bounds__(1024) void k_reduce(const float* __restrict__ nll,
                                                 float* __restrict__ out, int B) {
    __shared__ float red[16];
    const int tid = threadIdx.x;
    const float4* __restrict__ n4 = (const float4*)nll;
    float s = 0.f;
    for (int i = tid; i < B / 4; i += 1024) {
        float4 v = n4[i];
        s += (v.x + v.y) + (v.z + v.w);
    }
    s = wave_sum(s);
    if ((tid & 63) == 0) red[tid >> 6] = s;
    __syncthreads();
    if (tid == 0) {
        float tsum = 0.f;
        #pragma unroll
        for (int k = 0; k < 16; ++k) tsum += red[k];
        out[0] = tsum / (float)B;
    }
}

extern "C" void kernel_launch(void* const* d_in, const int* in_sizes, int n_in,
                              void* d_out, int out_size, void* d_ws, size_t ws_size,
                              hipStream_t stream) {
    const float* outp = (const float*)d_in[0];   // [B, C] f32
    const int*   tg   = (const int*)d_in[1];     // [B] i32
    float*       out  = (float*)d_out;           // scalar f32

    const int B = in_sizes[1];                   // 8192 (C fixed at 4096)

    char*  ws     = (char*)d_ws;
    float* logacc = (float*)ws;                  // 16 KB
    float* nll    = (float*)(ws + 16384);        // B*4 = 32 KB

    k_hist  <<<1, 1024, 0, stream>>>(tg, B, logacc);
    k_row   <<<B, 256, 0, stream>>>(outp, tg, logacc, nll);
    k_reduce<<<1, 1024, 0, stream>>>(nll, out, B);
}

// Round 10
// 35.657 us; speedup vs baseline: 1.6223x; 1.0874x over previous
//
#include <hip/hip_runtime.h>
#include <math.h>

// SeesawLoss forward: B=8192 rows, C=4096 classes, P=0.8, Q=2.0, EPS=0.01
// nll_b = M2 + log(sum_j exp(logit_bj - M2)) - o_{b,t}
// Key algebra this round (removes ALL pass-3 transcendentals):
//   exp(logit_j - M2) = e_j * d * mit_j * comp_j
//     e_j    = exp(o_j - m_lane)            (computed once in pass 2, reused)
//     d      = exp(m_lane - M2)             (1 exp per lane)
//     c      = exp(m_lane - Koff)           (1 exp per lane)
//     comp_j = max((e_j*c)^2, 1)            (Q=2.0 -> square, no pow)
//     mit_j  = min(powacc_j / powacc_t, 1)  (powacc = acc^0.8 table; x^0.8
//                                            monotone -> predicate preserved)
//   Koff = M + lse1 + max(o_t - M - lse1, log(EPS));  M2 = M + max(0,2(M-Koff))
//   (M2 is an analytic upper bound on all logits -> no 3rd reduction pass.)
// Structure: block-per-row, 16 floats/thread in 4 named float4s (rule #20;
// R8 showed 64 floats/lane spills). e_j overwrites v in place -> no extra
// row-sized register set. NO grid-wide atomics (R4/R5: same-address atomics
// + fence from 8192 blocks serialize ~670us across 8 XCDs).

#define CC 4096

__device__ __forceinline__ float wave_sum(float v) {
    #pragma unroll
    for (int o = 32; o > 0; o >>= 1) v += __shfl_xor(v, o, 64);
    return v;
}

// online-softmax merge: (m,s) <- merge((m,s),(m2,s2))
__device__ __forceinline__ void ms_merge(float& m, float& s, float m2, float s2) {
    float Mn = fmaxf(m, m2);
    s = s * __expf(m - Mn) + s2 * __expf(m2 - Mn);
    m = Mn;
}

// exp each component against lane max (in place), return component sum
__device__ __forceinline__ float exp4(float4& v, float m) {
    v.x = __expf(v.x - m); v.y = __expf(v.y - m);
    v.z = __expf(v.z - m); v.w = __expf(v.w - m);
    return (v.x + v.y) + (v.z + v.w);
}

// pass-3 term sum for one float4 of e-values (pure VALU, no transcendentals)
__device__ __forceinline__ float zsum4(float4 e, float4 pa, float rt,
                                       float c, float d) {
    float srx = e.x * c, sry = e.y * c, srz = e.z * c, srw = e.w * c;
    float cpx = fmaxf(srx * srx, 1.f), cpy = fmaxf(sry * sry, 1.f);
    float cpz = fmaxf(srz * srz, 1.f), cpw = fmaxf(srw * srw, 1.f);
    float mtx = fminf(pa.x * rt, 1.f), mty = fminf(pa.y * rt, 1.f);
    float mtz = fminf(pa.z * rt, 1.f), mtw = fminf(pa.w * rt, 1.f);
    float tx = (e.x * d) * (mtx * cpx), ty = (e.y * d) * (mty * cpy);
    float tz = (e.z * d) * (mtz * cpz), tw = (e.w * d) * (mtw * cpw);
    return (tx + ty) + (tz + tw);
}

// One block: bincount via LDS atomics -> clamp -> powacc = acc^0.8 table.
__global__ __launch_bounds__(1024) void k_hist(const int* __restrict__ tg, int B,
                                               float* __restrict__ powacc) {
    __shared__ int hacc[CC];
    const int tid = threadIdx.x;
    #pragma unroll
    for (int k = 0; k < CC / 1024; ++k) hacc[tid + k * 1024] = 0;
    __syncthreads();
    const int4* __restrict__ tg4 = (const int4*)tg;
    for (int i = tid; i < B / 4; i += 1024) {
        int4 tv = tg4[i];
        atomicAdd(&hacc[tv.x], 1); atomicAdd(&hacc[tv.y], 1);
        atomicAdd(&hacc[tv.z], 1); atomicAdd(&hacc[tv.w], 1);
    }
    __syncthreads();
    #pragma unroll
    for (int k = 0; k < CC / 1024; ++k) {
        int i = tid + k * 1024;
        int a = hacc[i];
        if (a < 1) a = 1;                       // clamp(min=1)
        powacc[i] = __powf((float)a, 0.8f);     // acc^P
    }
}

__global__ __launch_bounds__(256, 8) void k_row(const float* __restrict__ outp,
                                                const int* __restrict__ tg,
                                                const float* __restrict__ powacc,
                                                float* __restrict__ nll) {
    __shared__ float2 red_ms[4];
    __shared__ float  red_z[4];

    const int b   = blockIdx.x;
    const int tid = threadIdx.x;
    const int w   = tid >> 6;
    const bool lane0 = (tid & 63) == 0;

    const float LOG_EPS = -4.605170185988091f;   // log(0.01)

    // scalar chain early (critical path to Koff / rt)
    const int   t    = tg[b];
    const float o_t  = outp[(size_t)b * CC + t];
    const float pa_t = powacc[t];

    const float4* __restrict__ src = (const float4*)(outp + (size_t)b * CC);
    const float4* __restrict__ pac = (const float4*)powacc;

    // ---- row into registers (16 floats/thread, named — rule #20) ----
    float4 v0 = src[tid];
    float4 v1 = src[tid + 256];
    float4 v2 = src[tid + 512];
    float4 v3 = src[tid + 768];

    // ---- lane-local max; e_j = exp(o_j - m_lane) in place ----
    float m0 = fmaxf(fmaxf(v0.x, v0.y), fmaxf(v0.z, v0.w));
    float m1 = fmaxf(fmaxf(v1.x, v1.y), fmaxf(v1.z, v1.w));
    float m2 = fmaxf(fmaxf(v2.x, v2.y), fmaxf(v2.z, v2.w));
    float m3 = fmaxf(fmaxf(v3.x, v3.y), fmaxf(v3.z, v3.w));
    const float mlane = fmaxf(fmaxf(m0, m1), fmaxf(m2, m3));
    float s = (exp4(v0, mlane) + exp4(v1, mlane)) +
              (exp4(v2, mlane) + exp4(v3, mlane));   // v* now hold e_j

    // ---- joint (m,s) wave reduction, then cross-wave via LDS ----
    float m = mlane;
    #pragma unroll
    for (int o = 32; o > 0; o >>= 1) {
        float mo = __shfl_xor(m, o, 64);
        float so = __shfl_xor(s, o, 64);
        ms_merge(m, s, mo, so);
    }
    if (lane0) red_ms[w] = make_float2(m, s);
    __syncthreads();
    float M = red_ms[0].x, S = red_ms[0].y;
    ms_merge(M, S, red_ms[1].x, red_ms[1].y);
    ms_merge(M, S, red_ms[2].x, red_ms[2].y);
    ms_merge(M, S, red_ms[3].x, red_ms[3].y);
    const float lse1 = __logf(S);

    const float ls_t    = o_t - M - lse1;
    const float logclip = fmaxf(ls_t, LOG_EPS);
    const float Koff    = M + lse1 + logclip;                // score_j/clip = exp(o_j-Koff)
    const float M2      = M + fmaxf(0.f, 2.0f * (M - Koff)); // analytic logit bound

    // per-lane scale factors (2 exp + 1 div per lane, not per element)
    const float c  = __expf(mlane - Koff);     // e_j*c = exp(o_j - Koff) <= 100
    const float d  = __expf(mlane - M2);       // e_j*d = exp(o_j - M2)   <= 1
    const float rt = __fdividef(1.0f, pa_t);

    // ---- pass 3: pure-VALU seesaw terms, 4 independent accumulators ----
    float z0 = zsum4(v0, pac[tid      ], rt, c, d);
    float z1 = zsum4(v1, pac[tid + 256], rt, c, d);
    float z2 = zsum4(v2, pac[tid + 512], rt, c, d);
    float z3 = zsum4(v3, pac[tid + 768], rt, c, d);
    float z  = wave_sum((z0 + z1) + (z2 + z3));
    if (lane0) red_z[w] = z;
    __syncthreads();

    if (tid == 0) {
        float S2 = (red_z[0] + red_z[1]) + (red_z[2] + red_z[3]);
        nll[b] = M2 + __logf(S2) - o_t;        // plain store, no atomics
    }
}

// deterministic final mean: fixed strided partials + fixed tree
__global__ __launch_bounds__(1024) void k_reduce(const float* __restrict__ nll,
                                                 float* __restrict__ out, int B) {
    __shared__ float red[16];
    const int tid = threadIdx.x;
    const float4* __restrict__ n4 = (const float4*)nll;
    float s = 0.f;
    for (int i = tid; i < B / 4; i += 1024) {
        float4 v = n4[i];
        s += (v.x + v.y) + (v.z + v.w);
    }
    s = wave_sum(s);
    if ((tid & 63) == 0) red[tid >> 6] = s;
    __syncthreads();
    if (tid == 0) {
        float tsum = 0.f;
        #pragma unroll
        for (int k = 0; k < 16; ++k) tsum += red[k];
        out[0] = tsum / (float)B;
    }
}

extern "C" void kernel_launch(void* const* d_in, const int* in_sizes, int n_in,
                              void* d_out, int out_size, void* d_ws, size_t ws_size,
                              hipStream_t stream) {
    const float* outp = (const float*)d_in[0];   // [B, C] f32
    const int*   tg   = (const int*)d_in[1];     // [B] i32
    float*       out  = (float*)d_out;           // scalar f32

    const int B = in_sizes[1];                   // 8192 (C fixed at 4096)

    char*  ws     = (char*)d_ws;
    float* powacc = (float*)ws;                  // 16 KB
    float* nll    = (float*)(ws + 16384);        // B*4 = 32 KB

    k_hist  <<<1, 1024, 0, stream>>>(tg, B, powacc);
    k_row   <<<B, 256, 0, stream>>>(outp, tg, powacc, nll);
    k_reduce<<<1, 1024, 0, stream>>>(nll, out, B);
}

// Round 11
// 34.287 us; speedup vs baseline: 1.6871x; 1.0400x over previous
//
#include <hip/hip_runtime.h>
#include <math.h>

// SeesawLoss forward: B=8192 rows, C=4096 classes, P=0.8, Q=2.0, EPS=0.01
// Full log-space algebra (this round removes M2 entirely):
//   L    = logsumexp(o) ;  p_t = exp(o_t - L)
//   Koff = L + log(max(p_t, EPS))          (so g_j = exp(o_j-Koff) = sratio_j)
//   exp(logit_j - Koff) = mit_j * max(g_j^3, g_j)        [Q=2: comp=max(g^2,1)]
//   mit_j = min(powacc_j/powacc_t, 1)      [powacc = acc^0.8; x^0.8 monotone]
//   nll_b = Koff + log(Z) - o_t,  Z = sum_j mit_j*max(g_j^3, g_j)
// Range-safe: g <= exp(4.6) = 100 -> Z <= 4e9 (f32 ok); Z >= g_t > 0.
// At j==t: g_t <= 1 and mit_t = 1 -> term = g_t, matching the (1-onehot) mask.
//
// Structure: block-per-row, 16 floats/thread in 4 named float4s (rule #20;
// R8: 64 floats/lane -> spill disaster). powacc prefetched WITH the row
// (8 loads in flight, ~56 VGPR <= 64 so 8 blocks/CU holds). Max-reduce
// (LDS/shfl pipe) overlaps the exp pass (trans pipe); sum scaled once by
// exp(m_lane - mw) instead of per-merge-step exps. NO grid-wide atomics
// (R4/R5: same-address atomics + fence from 8192 blocks -> ~670us serial).

#define CC 4096

__device__ __forceinline__ float wave_max(float v) {
    #pragma unroll
    for (int o = 32; o > 0; o >>= 1) v = fmaxf(v, __shfl_xor(v, o, 64));
    return v;
}
__device__ __forceinline__ float wave_sum(float v) {
    #pragma unroll
    for (int o = 32; o > 0; o >>= 1) v += __shfl_xor(v, o, 64);
    return v;
}

// exp each component against lane max (in place), return component sum
__device__ __forceinline__ float exp4(float4& v, float m) {
    v.x = __expf(v.x - m); v.y = __expf(v.y - m);
    v.z = __expf(v.z - m); v.w = __expf(v.w - m);
    return (v.x + v.y) + (v.z + v.w);
}

// pass-3 term sum for one float4 of e-values (8 VALU ops/element, no trans)
__device__ __forceinline__ float zsum4(float4 e, float4 pa, float rt, float c) {
    float gx = e.x * c, gy = e.y * c, gz = e.z * c, gw = e.w * c;
    float hx = fmaxf(gx * gx * gx, gx), hy = fmaxf(gy * gy * gy, gy);
    float hz = fmaxf(gz * gz * gz, gz), hw = fmaxf(gw * gw * gw, gw);
    float mx = fminf(pa.x * rt, 1.f),  my = fminf(pa.y * rt, 1.f);
    float mz = fminf(pa.z * rt, 1.f),  mw = fminf(pa.w * rt, 1.f);
    return (hx * mx + hy * my) + (hz * mz + hw * mw);
}

// One block: bincount via LDS atomics -> clamp -> powacc = acc^0.8 table.
__global__ __launch_bounds__(1024) void k_hist(const int* __restrict__ tg, int B,
                                               float* __restrict__ powacc) {
    __shared__ int hacc[CC];
    const int tid = threadIdx.x;
    #pragma unroll
    for (int k = 0; k < CC / 1024; ++k) hacc[tid + k * 1024] = 0;
    __syncthreads();
    const int4* __restrict__ tg4 = (const int4*)tg;
    for (int i = tid; i < B / 4; i += 1024) {
        int4 tv = tg4[i];
        atomicAdd(&hacc[tv.x], 1); atomicAdd(&hacc[tv.y], 1);
        atomicAdd(&hacc[tv.z], 1); atomicAdd(&hacc[tv.w], 1);
    }
    __syncthreads();
    #pragma unroll
    for (int k = 0; k < CC / 1024; ++k) {
        int i = tid + k * 1024;
        int a = hacc[i];
        if (a < 1) a = 1;                       // clamp(min=1)
        powacc[i] = __powf((float)a, 0.8f);     // acc^P
    }
}

__global__ __launch_bounds__(256, 8) void k_row(const float* __restrict__ outp,
                                                const int* __restrict__ tg,
                                                const float* __restrict__ powacc,
                                                float* __restrict__ nll) {
    __shared__ float2 red_ms[4];
    __shared__ float  red_z[4];

    const int b   = blockIdx.x;
    const int tid = threadIdx.x;
    const int w   = tid >> 6;
    const bool lane0 = (tid & 63) == 0;

    const float LOG_EPS = -4.605170185988091f;   // log(0.01)

    // scalar chain early (critical path to Koff / rt)
    const int   t    = tg[b];
    const float o_t  = outp[(size_t)b * CC + t];
    const float pa_t = powacc[t];

    const float4* __restrict__ src = (const float4*)(outp + (size_t)b * CC);
    const float4* __restrict__ pac = (const float4*)powacc;

    // ---- all 8 loads issued together: row + powacc prefetch (rule #20 safe) ----
    float4 v0 = src[tid];
    float4 v1 = src[tid + 256];
    float4 v2 = src[tid + 512];
    float4 v3 = src[tid + 768];
    float4 pa0 = pac[tid];
    float4 pa1 = pac[tid + 256];
    float4 pa2 = pac[tid + 512];
    float4 pa3 = pac[tid + 768];

    // ---- lane-local max ----
    float m0 = fmaxf(fmaxf(v0.x, v0.y), fmaxf(v0.z, v0.w));
    float m1 = fmaxf(fmaxf(v1.x, v1.y), fmaxf(v1.z, v1.w));
    float m2 = fmaxf(fmaxf(v2.x, v2.y), fmaxf(v2.z, v2.w));
    float m3 = fmaxf(fmaxf(v3.x, v3.y), fmaxf(v3.z, v3.w));
    const float mlane = fmaxf(fmaxf(m0, m1), fmaxf(m2, m3));

    // wave max (LDS/shfl pipe) overlaps the exp pass (trans pipe)
    const float mw = wave_max(mlane);

    // e_j = exp(o_j - m_lane) in place; lane-relative sum
    float s = (exp4(v0, mlane) + exp4(v1, mlane)) +
              (exp4(v2, mlane) + exp4(v3, mlane));

    // rebase once to wave max, then plain sum-reduce
    float S_w = wave_sum(s * __expf(mlane - mw));
    if (lane0) red_ms[w] = make_float2(mw, S_w);
    __syncthreads();

    // cross-wave merge: max tree + 4 parallel exps (uniform on all threads)
    const float M = fmaxf(fmaxf(red_ms[0].x, red_ms[1].x),
                          fmaxf(red_ms[2].x, red_ms[3].x));
    const float S = red_ms[0].y * __expf(red_ms[0].x - M)
                  + red_ms[1].y * __expf(red_ms[1].x - M)
                  + red_ms[2].y * __expf(red_ms[2].x - M)
                  + red_ms[3].y * __expf(red_ms[3].x - M);
    const float L       = M + __logf(S);                 // true logsumexp
    const float logclip = fmaxf(o_t - L, LOG_EPS);       // log(max(p_t, EPS))
    const float Koff    = L + logclip;                   // g_j = exp(o_j - Koff)

    const float c  = __expf(mlane - Koff);               // g_j = e_j * c
    const float rt = __fdividef(1.0f, pa_t);

    // ---- pass 3: pure-VALU seesaw terms, 4 independent accumulators ----
    float z0 = zsum4(v0, pa0, rt, c);
    float z1 = zsum4(v1, pa1, rt, c);
    float z2 = zsum4(v2, pa2, rt, c);
    float z3 = zsum4(v3, pa3, rt, c);
    float z  = wave_sum((z0 + z1) + (z2 + z3));
    if (lane0) red_z[w] = z;
    __syncthreads();

    if (tid == 0) {
        float Z = (red_z[0] + red_z[1]) + (red_z[2] + red_z[3]);
        nll[b] = Koff + __logf(Z) - o_t;       // plain store, no atomics
    }
}

// deterministic final mean: fixed strided partials + fixed tree
__global__ __launch_bounds__(1024) void k_reduce(const float* __restrict__ nll,
                                                 float* __restrict__ out, int B) {
    __shared__ float red[16];
    const int tid = threadIdx.x;
    const float4* __restrict__ n4 = (const float4*)nll;
    float s = 0.f;
    for (int i = tid; i < B / 4; i += 1024) {
        float4 v = n4[i];
        s += (v.x + v.y) + (v.z + v.w);
    }
    s = wave_sum(s);
    if ((tid & 63) == 0) red[tid >> 6] = s;
    __syncthreads();
    if (tid == 0) {
        float tsum = 0.f;
        #pragma unroll
        for (int k = 0; k < 16; ++k) tsum += red[k];
        out[0] = tsum / (float)B;
    }
}

extern "C" void kernel_launch(void* const* d_in, const int* in_sizes, int n_in,
                              void* d_out, int out_size, void* d_ws, size_t ws_size,
                              hipStream_t stream) {
    const float* outp = (const float*)d_in[0];   // [B, C] f32
    const int*   tg   = (const int*)d_in[1];     // [B] i32
    float*       out  = (float*)d_out;           // scalar f32

    const int B = in_sizes[1];                   // 8192 (C fixed at 4096)

    char*  ws     = (char*)d_ws;
    float* powacc = (float*)ws;                  // 16 KB
    float* nll    = (float*)(ws + 16384);        // B*4 = 32 KB

    k_hist  <<<1, 1024, 0, stream>>>(tg, B, powacc);
    k_row   <<<B, 256, 0, stream>>>(outp, tg, powacc, nll);
    k_reduce<<<1, 1024, 0, stream>>>(nll, out, B);
}